// Round 6
// baseline (393.586 us; speedup 1.0000x reference)
//
#include <hip/hip_runtime.h>
#include <hip/hip_bf16.h>

#define NUM_GRAPHS 1024
#define NUM_ATOMS  64

// Native clang vector type (__builtin_nontemporal_load requires it).
typedef float f4 __attribute__((ext_vector_type(4)));

// Kernel 0: segment boundaries via parallel transition scan, int4-vectorized.
// offs[g] = first node index of graph g; offs[1024] = N. Also zeroes the
// ready-counter used by the fused finalize (ws is not re-poisoned between
// replays, so we must establish counter=0 deterministically every call).
__global__ void __launch_bounds__(256)
bounds_scan_kernel(const int* __restrict__ batch, int* __restrict__ offs,
                   int* __restrict__ counter, int total_nodes) {
    int i = blockIdx.x * blockDim.x + threadIdx.x;
    long long base = (long long)i * 4;
    if (base >= total_nodes) return;
    if (i == 0) *counter = 0;

    int e[4];
    int m = (int)((total_nodes - base < 4) ? (total_nodes - base) : 4);
    if (m == 4) {
        int4 v = ((const int4*)batch)[i];
        e[0] = v.x; e[1] = v.y; e[2] = v.z; e[3] = v.w;
    } else {
        for (int k = 0; k < m; ++k) e[k] = batch[base + k];
    }

    if (base == 0) {
        for (int g = 0; g <= e[0]; ++g) offs[g] = 0;
    }
    for (int k = 1; k < m; ++k) {
        if (e[k] != e[k - 1]) {
            for (int g = e[k - 1] + 1; g <= e[k]; ++g) offs[g] = (int)(base + k);
        }
    }
    if (base + m < total_nodes) {
        int nb = batch[base + m];
        if (nb != e[m - 1]) {
            for (int g = e[m - 1] + 1; g <= nb; ++g) offs[g] = (int)(base + m);
        }
    } else {
        for (int g = e[m - 1] + 1; g <= NUM_GRAPHS; ++g) offs[g] = total_nodes;
    }
}

// Kernel 1: one block per graph. Stream-reduce codes[s0:s1, :] with nt loads,
// write the mean; the LAST block to finish (device atomic counter) computes
// the per-atom unbiased variance over all 1024 means, the atom-mean, * -0.01.
// Block = 512 threads: t = 16*q + r, q in [0,32) node sub-index, r in [0,16)
// f4 column group.
__global__ void __launch_bounds__(512)
graph_mean_kernel(const f4* __restrict__ codes4,     // [nodes][16] f4
                  const int* __restrict__ offs,      // [NUM_GRAPHS+1]
                  f4* __restrict__ means,            // [NUM_GRAPHS][16] f4
                  int* __restrict__ counter,
                  float* __restrict__ out,
                  int total_nodes) {
    int g = blockIdx.x;
    int s0 = offs[g];
    int s1 = offs[g + 1];

    int t = threadIdx.x;
    int r = t & 15;
    int q = t >> 4;

    const f4* p = codes4 + (long long)(s0 + q) * 16 + r;
    int n = s0 + q;

    f4 a0 = (f4)(0.f), a1 = (f4)(0.f), a2 = (f4)(0.f), a3 = (f4)(0.f);

    while (n + 96 < s1) {
        f4 v0 = __builtin_nontemporal_load(p);
        f4 v1 = __builtin_nontemporal_load(p + 512);
        f4 v2 = __builtin_nontemporal_load(p + 1024);
        f4 v3 = __builtin_nontemporal_load(p + 1536);
        a0 += v0; a1 += v1; a2 += v2; a3 += v3;
        n += 128; p += 2048;
    }
    while (n < s1) {
        f4 v = __builtin_nontemporal_load(p);
        a0 += v;
        n += 32; p += 512;
    }

    f4 acc = (a0 + a1) + (a2 + a3);

    __shared__ f4 red[32][17];
    red[q][r] = acc;
    __syncthreads();

    if (t < 16) {
        f4 tot = (f4)(0.f);
        #pragma unroll
        for (int k = 0; k < 32; k++) tot += red[k][t];
        float inv = 1.0f / (float)(s1 - s0);
        means[g * 16 + t] = tot * inv;
    }

    // ---- last-block finalize ----
    __threadfence();              // make this block's means visible device-wide
    __syncthreads();              // all threads' fences complete
    __shared__ int isLast;
    if (t == 0) {
        int old = atomicAdd(counter, 1);
        isLast = (old == (int)gridDim.x - 1);
    }
    __syncthreads();
    if (!isLast) return;
    __threadfence();              // acquire: see all other blocks' means

    // 512 threads: a4 = t&15 (f4 column), grp = t>>4 in [0,32).
    __shared__ f4 S1[32][17];
    __shared__ f4 S2[32][17];
    __shared__ f4 V4[16];

    int a4  = t & 15;
    int grp = t >> 4;

    f4 s1v = (f4)(0.f);
    f4 s2v = (f4)(0.f);
    for (int gg = grp; gg < NUM_GRAPHS; gg += 32) {
        f4 v = means[gg * 16 + a4];
        s1v += v;
        s2v += v * v;
    }
    S1[grp][a4] = s1v;
    S2[grp][a4] = s2v;
    __syncthreads();

    if (t < 16) {
        f4 t1 = (f4)(0.f);
        f4 t2 = (f4)(0.f);
        #pragma unroll
        for (int k = 0; k < 32; k++) { t1 += S1[k][t]; t2 += S2[k][t]; }
        const float invN  = 1.0f / NUM_GRAPHS;
        const float invN1 = 1.0f / (NUM_GRAPHS - 1);
        V4[t] = (t2 - t1 * t1 * invN) * invN1;   // unbiased variance, 4 atoms
    }
    __syncthreads();

    if (t == 0) {
        float tot = 0.f;
        #pragma unroll
        for (int k = 0; k < 16; k++) {
            f4 v = V4[k];
            tot += (v.x + v.y) + (v.z + v.w);
        }
        out[0] = -0.01f * (tot * (1.0f / NUM_ATOMS));
    }
}

extern "C" void kernel_launch(void* const* d_in, const int* in_sizes, int n_in,
                              void* d_out, int out_size, void* d_ws, size_t ws_size,
                              hipStream_t stream) {
    const float* codes = (const float*)d_in[0];
    const int*   batch = (const int*)d_in[1];
    int total_nodes = in_sizes[0] / NUM_ATOMS;

    f4*  means   = (f4*)d_ws;                                            // 256 KB
    int* offs    = (int*)((char*)d_ws + NUM_GRAPHS * 16 * sizeof(f4));   // 4.1 KB
    int* counter = offs + (NUM_GRAPHS + 1);

    int nquads = (total_nodes + 3) / 4;
    bounds_scan_kernel<<<(nquads + 255) / 256, 256, 0, stream>>>(
        batch, offs, counter, total_nodes);

    graph_mean_kernel<<<NUM_GRAPHS, 512, 0, stream>>>(
        (const f4*)codes, offs, means, counter, (float*)d_out, total_nodes);
}

// Round 7
// 95.811 us; speedup vs baseline: 4.1079x; 4.1079x over previous
//
#include <hip/hip_runtime.h>
#include <hip/hip_bf16.h>

#define NUM_GRAPHS 1024
#define NUM_ATOMS  64

// Native clang vector type (__builtin_nontemporal_load requires it).
typedef float f4 __attribute__((ext_vector_type(4)));

// Kernel 0: segment boundaries via parallel transition scan, int4-vectorized.
// offs[g] = first node index of graph g; offs[1024] = N.
// NOTE (round 6 lesson): no cross-block fences anywhere in this pipeline —
// device-scope release fences emit per-block L2 writebacks on gfx950 (XCD L2s
// are non-coherent) and cost ~300 us across 1024 blocks.
__global__ void __launch_bounds__(256)
bounds_scan_kernel(const int* __restrict__ batch, int* __restrict__ offs, int total_nodes) {
    int i = blockIdx.x * blockDim.x + threadIdx.x;
    long long base = (long long)i * 4;
    if (base >= total_nodes) return;

    int e[4];
    int m = (int)((total_nodes - base < 4) ? (total_nodes - base) : 4);
    if (m == 4) {
        int4 v = ((const int4*)batch)[i];
        e[0] = v.x; e[1] = v.y; e[2] = v.z; e[3] = v.w;
    } else {
        for (int k = 0; k < m; ++k) e[k] = batch[base + k];
    }

    if (base == 0) {
        for (int g = 0; g <= e[0]; ++g) offs[g] = 0;
    }
    for (int k = 1; k < m; ++k) {
        if (e[k] != e[k - 1]) {
            for (int g = e[k - 1] + 1; g <= e[k]; ++g) offs[g] = (int)(base + k);
        }
    }
    if (base + m < total_nodes) {
        int nb = batch[base + m];
        if (nb != e[m - 1]) {
            for (int g = e[m - 1] + 1; g <= nb; ++g) offs[g] = (int)(base + m);
        }
    } else {
        for (int g = e[m - 1] + 1; g <= NUM_GRAPHS; ++g) offs[g] = total_nodes;
    }
}

// Kernel 1: one block per graph. Stream-reduce codes[s0:s1, :] with nt loads,
// write the per-graph mean. Block = 512 threads: t = 16*q + r, q in [0,32)
// node sub-index, r in [0,16) f4 column group. 4x unrolled.
__global__ void __launch_bounds__(512)
graph_mean_kernel(const f4* __restrict__ codes4,     // [nodes][16] f4
                  const int* __restrict__ offs,      // [NUM_GRAPHS+1]
                  f4* __restrict__ means,            // [NUM_GRAPHS][16] f4
                  int total_nodes) {
    int g = blockIdx.x;
    int s0 = offs[g];
    int s1 = offs[g + 1];

    int t = threadIdx.x;
    int r = t & 15;
    int q = t >> 4;

    const f4* p = codes4 + (long long)(s0 + q) * 16 + r;
    int n = s0 + q;

    f4 a0 = (f4)(0.f), a1 = (f4)(0.f), a2 = (f4)(0.f), a3 = (f4)(0.f);

    while (n + 96 < s1) {
        f4 v0 = __builtin_nontemporal_load(p);
        f4 v1 = __builtin_nontemporal_load(p + 512);
        f4 v2 = __builtin_nontemporal_load(p + 1024);
        f4 v3 = __builtin_nontemporal_load(p + 1536);
        a0 += v0; a1 += v1; a2 += v2; a3 += v3;
        n += 128; p += 2048;
    }
    while (n < s1) {
        f4 v = __builtin_nontemporal_load(p);
        a0 += v;
        n += 32; p += 512;
    }

    f4 acc = (a0 + a1) + (a2 + a3);

    __shared__ f4 red[32][17];
    red[q][r] = acc;
    __syncthreads();

    if (t < 16) {
        f4 tot = (f4)(0.f);
        #pragma unroll
        for (int k = 0; k < 32; k++) tot += red[k][t];
        float inv = 1.0f / (float)(s1 - s0);
        means[g * 16 + t] = tot * inv;
    }
}

// Kernel 2: per-atom unbiased variance over 1024 graph means, mean over atoms,
// * -0.01. One block, 1024 threads, f4-vectorized.
__global__ void __launch_bounds__(1024)
finalize_kernel(const f4* __restrict__ means4,  // [NUM_GRAPHS][16] f4
                float* __restrict__ out) {
    __shared__ f4 S1[64][17];
    __shared__ f4 S2[64][17];
    __shared__ f4 V4[16];

    int t = threadIdx.x;
    int a4  = t & 15;   // f4 column (atoms 4*a4 .. 4*a4+3)
    int grp = t >> 4;   // graph group, [0,64)

    f4 s1 = (f4)(0.f);
    f4 s2 = (f4)(0.f);
    for (int g = grp; g < NUM_GRAPHS; g += 64) {
        f4 v = means4[g * 16 + a4];
        s1 += v;
        s2 += v * v;
    }
    S1[grp][a4] = s1;
    S2[grp][a4] = s2;
    __syncthreads();

    if (t < 16) {
        f4 t1 = (f4)(0.f);
        f4 t2 = (f4)(0.f);
        #pragma unroll
        for (int k = 0; k < 64; k++) { t1 += S1[k][t]; t2 += S2[k][t]; }
        const float invN  = 1.0f / NUM_GRAPHS;
        const float invN1 = 1.0f / (NUM_GRAPHS - 1);
        V4[t] = (t2 - t1 * t1 * invN) * invN1;
    }
    __syncthreads();

    if (t == 0) {
        float tot = 0.f;
        #pragma unroll
        for (int k = 0; k < 16; k++) {
            f4 v = V4[k];
            tot += (v.x + v.y) + (v.z + v.w);
        }
        out[0] = -0.01f * (tot * (1.0f / NUM_ATOMS));
    }
}

extern "C" void kernel_launch(void* const* d_in, const int* in_sizes, int n_in,
                              void* d_out, int out_size, void* d_ws, size_t ws_size,
                              hipStream_t stream) {
    const float* codes = (const float*)d_in[0];
    const int*   batch = (const int*)d_in[1];
    int total_nodes = in_sizes[0] / NUM_ATOMS;

    f4*  means = (f4*)d_ws;                                             // 256 KB
    int* offs  = (int*)((char*)d_ws + NUM_GRAPHS * 16 * sizeof(f4));    // 4.1 KB

    int nquads = (total_nodes + 3) / 4;
    bounds_scan_kernel<<<(nquads + 255) / 256, 256, 0, stream>>>(batch, offs, total_nodes);

    graph_mean_kernel<<<NUM_GRAPHS, 512, 0, stream>>>(
        (const f4*)codes, offs, means, total_nodes);

    finalize_kernel<<<1, 1024, 0, stream>>>((const f4*)means, (float*)d_out);
}